// Round 3
// baseline (7809.982 us; speedup 1.0000x reference)
//
#include <hip/hip_runtime.h>
#include <stdint.h>

// Problem constants (fixed seed, fixed shapes)
#define BB 16
#define TT 2048
#define NI 32
#define NN 2048
#define NO 32
#define WASH 64
#define TO (TT - WASH + 1)   // 1985
#define W 24                 // per-row ELL cap
#define WT 24                // per-thread combined (pair) slot count — COMPILE-TIME trip count
#define CH 16                // time-chunk for fused MFMA GEMMs
#define UST 18               // u_lds row stride (halfwords) -> dword stride 9 (coprime 32)
#define HBST 2056            // hb row stride (halfwords) = 2048 + 8 padding

typedef short bfvec __attribute__((ext_vector_type(8)));   // 8 bf16 in 4 VGPRs
typedef float f4_t  __attribute__((ext_vector_type(4)));

__device__ inline unsigned short f2bf(float f) {
  unsigned int u = __builtin_bit_cast(unsigned int, f);
  unsigned int r = u + 0x7fffu + ((u >> 16) & 1u);   // RNE
  return (unsigned short)(r >> 16);
}
__device__ inline float bf2f(unsigned short s) {
  unsigned int u = ((unsigned int)s) << 16;
  return __builtin_bit_cast(float, u);
}
__device__ inline float tanh_fast(float x) {
  x = fminf(15.f, fmaxf(-15.f, x));
  float e = __expf(x + x);
  float r = __builtin_amdgcn_rcpf(e + 1.0f);
  return (e - 1.0f) * r;
}

// ---------------- K1: dense A -> packed ELL (bf16 val << 16 | byte-offset col, NATURAL cols) ----
__global__ void build_ell(const float* __restrict__ A, uint32_t* __restrict__ ell,
                          uint32_t* __restrict__ deg) {
  int gw = (int)((blockIdx.x * blockDim.x + threadIdx.x) >> 6);  // one wave per row
  int lane = (int)(threadIdx.x & 63);
  if (gw >= NN) return;
  const float* row = A + (size_t)gw * NN;
  int base = 0;
  for (int c = 0; c < NN; c += 64) {
    float v = row[c + lane];
    bool nz = (v != 0.0f);
    unsigned long long mask = __ballot(nz);
    int pre = __popcll(mask & ((1ull << lane) - 1ull));
    if (nz) {
      int idx = base + pre;
      if (idx < W) {
        uint32_t packed = (((uint32_t)f2bf(v)) << 16) | (uint32_t)((c + lane) * 4);
        ell[(size_t)gw * W + idx] = packed;
      }
    }
    base += __popcll(mask);
  }
  int d = base < W ? base : W;
  if (lane == 0) deg[gw] = (uint32_t)d;
  for (int k = d + lane; k < W; k += 64) ell[(size_t)gw * W + k] = 0u;
}

// ---------------- K2: DETERMINISTIC counting (rank) sort by degree -> perm, invp ----------------
__global__ void sortperm(const uint32_t* __restrict__ deg, uint32_t* __restrict__ perm,
                         uint32_t* __restrict__ invp) {
  __shared__ int dg[NN];
  int tid = (int)threadIdx.x;
  dg[tid] = (int)deg[tid];
  dg[tid + 1024] = (int)deg[tid + 1024];
  __syncthreads();
  for (int r = tid; r < NN; r += 1024) {
    int d = dg[r];
    int rank = 0;
    for (int j = 0; j < NN; ++j) {
      int dj = dg[j];
      rank += (dj < d) || (dj == d && j < r);
    }
    perm[rank] = (uint32_t)r;
    invp[r] = (uint32_t)rank;
  }
}

// ---------------- K2b: pair rows (tid, 2047-tid), bank-schedule combined entries into WT slots --
// One block per rec-wave (16 blocks x 64 threads). Entry order within a pair is free (sums
// commute); greedily assign entries to slots so each slot's 64 lanes spread over 32 banks.
// Pad: v=0, col = least-loaded bank. Output per rec-thread: WT x {byte addr, packed v0|v1}.
__global__ void schedule_pairs(const uint32_t* __restrict__ ell, const uint32_t* __restrict__ deg,
                               const uint32_t* __restrict__ perm, const uint32_t* __restrict__ invp,
                               uint32_t* __restrict__ pa, uint32_t* __restrict__ pv) {
  __shared__ uint32_t ccol[64][48];   // store-order col
  __shared__ uint32_t cvf[64][48];    // (v_bf16 << 16) | flag
  __shared__ uint32_t outa[64][WT];
  __shared__ uint32_t outv[64][WT];
  __shared__ int ncand[64];
  __shared__ unsigned long long used[64];
  int blk = (int)blockIdx.x;     // 0..15
  int t = (int)threadIdx.x;      // 0..63
  int tid = blk * 64 + t;        // rec thread id
  int n = 0;
  {
    int ro = (int)perm[tid];                 // row for y0 (flag 0)
    int d = (int)deg[ro]; if (d > W) d = W;
    for (int k = 0; k < d; ++k) {
      uint32_t e = ell[(size_t)ro * W + k];
      uint32_t col = (e & 0xffffu) >> 2;
      ccol[t][n] = invp[col];
      cvf[t][n] = (e & 0xffff0000u);
      ++n;
    }
    ro = (int)perm[2047 - tid];              // row for y1 (flag 1)
    d = (int)deg[ro]; if (d > W) d = W;
    for (int k = 0; k < d; ++k) {
      uint32_t e = ell[(size_t)ro * W + k];
      uint32_t col = (e & 0xffffu) >> 2;
      ccol[t][n] = invp[col];
      cvf[t][n] = (e & 0xffff0000u) | 1u;
      ++n;
    }
    ncand[t] = n;                            // <= 48; expected max ~18 (anti-correlated pairing)
    used[t] = 0ull;
  }
  __syncthreads();
  if (t == 0) {
    for (int s = 0; s < WT; ++s) {
      unsigned char bank_cnt[32];
      for (int b = 0; b < 32; ++b) bank_cnt[b] = 0;
      for (int i = 0; i < 64; ++i) {
        int r = (i + s * 19) & 63;   // rotate start lane per slot for fairness
        if (s < ncand[r]) {
          int sel = -1, selb = 0, best = 256;
          for (int k = 0; k < ncand[r]; ++k) {
            if ((used[r] >> k) & 1ull) continue;
            int b = (int)(ccol[r][k] & 31u);
            if ((int)bank_cnt[b] < best) { best = bank_cnt[b]; sel = k; selb = b; }
          }
          used[r] |= (1ull << (unsigned)sel);
          bank_cnt[selb]++;
          uint32_t vf = cvf[r][sel];
          outa[r][s] = ccol[r][sel] << 2;
          // flag 0 -> v in hi16 (y0), flag 1 -> v in lo16 (y1)
          outv[r][s] = (vf & 1u) ? (vf >> 16) : (vf & 0xffff0000u);
        } else {
          int bk = 0;
          for (int b = 1; b < 32; ++b) if (bank_cnt[b] < bank_cnt[bk]) bk = b;
          bank_cnt[bk]++;
          outa[r][s] = ((uint32_t)bk << 2);
          outv[r][s] = 0u;                   // both halves zero -> harmless
        }
      }
    }
  }
  __syncthreads();
  for (int k = 0; k < WT; ++k) {
    pa[(size_t)tid * WT + k] = outa[t][k];
    pv[(size_t)tid * WT + k] = outv[t][k];
  }
}

// ---------------- K3: Win/Wout -> MFMA B-fragment order (bf16 pairs), PERMUTED n ----------------
__global__ void build_frags(const float* __restrict__ Win, const float* __restrict__ Wout,
                            const uint32_t* __restrict__ perm,
                            uint32_t* __restrict__ winf, uint32_t* __restrict__ woutf) {
  int f = (int)(blockIdx.x * blockDim.x + threadIdx.x);  // 0..65535
  if (f < 32768) {
    int reg = f & 3, lane = (f >> 2) & 63, ntg = f >> 8;
    int n = (ntg << 4) + (lane & 15);
    int k = ((lane >> 4) << 3) + reg * 2;
    int np = (int)perm[n];
    uint32_t lo = f2bf(Win[(size_t)np * NI + k]);
    uint32_t hi = f2bf(Win[(size_t)np * NI + k + 1]);
    winf[f] = lo | (hi << 16);
  } else {
    int g = f - 32768;
    int reg = g & 3, lane = (g >> 2) & 63, kt = (g >> 8) & 63, ot = g >> 14;
    int o = (ot << 4) + (lane & 15);
    int n = (kt << 5) + ((lane >> 4) << 3) + reg * 2;
    uint32_t lo = f2bf(Wout[(size_t)o * NN + (int)perm[n]]);
    uint32_t hi = f2bf(Wout[(size_t)o * NN + (int)perm[n + 1]]);
    woutf[g] = lo | (hi << 16);
  }
}

// ---------------- K4: fused recurrence (1 workgroup per batch), store-order state ----------------
// LDS: h_a[2048]f32 | h_b[2048]f32 | u[2048][UST]bf16 (overlaid by out-scratch) | hb[CH][HBST]bf16
__global__ __launch_bounds__(1024, 4) void rec_kernel(
    const float* __restrict__ x,
    const uint32_t* __restrict__ pa, const uint32_t* __restrict__ pv,
    const uint32_t* __restrict__ winf, const uint32_t* __restrict__ woutf,
    float* __restrict__ out) {
  extern __shared__ char smem[];
  float* h_a = (float*)smem;                       //  8192 B
  float* h_b = (float*)(smem + 8192);              //  8192 B
  unsigned short* u_lds = (unsigned short*)(smem + 16384);      // 73728 B
  float* oscratch = (float*)(smem + 16384);                     // overlay (32768 B used)
  unsigned short* hb = (unsigned short*)(smem + 16384 + 73728); // 65792 B (total 155904)

  const int tid = (int)threadIdx.x;
  const int b = (int)blockIdx.x;
  const int lane = tid & 63;
  const int wv = tid >> 6;

  const int r0 = tid;            // store-order rows: all per-step writes conflict-free
  const int r1 = 2047 - tid;

  // Combined pair entry list -> REGISTERS (static trip count WT, no breaks -> no scratch)
  uint32_t ea[WT], ev[WT];
  {
    const uint4* qa = (const uint4*)(pa + (size_t)tid * WT);
    const uint4* qv = (const uint4*)(pv + (size_t)tid * WT);
    #pragma unroll
    for (int q = 0; q < WT / 4; ++q) {
      uint4 a4 = qa[q]; uint4 v4 = qv[q];
      ea[q*4+0]=a4.x; ea[q*4+1]=a4.y; ea[q*4+2]=a4.z; ea[q*4+3]=a4.w;
      ev[q*4+0]=v4.x; ev[q*4+1]=v4.y; ev[q*4+2]=v4.z; ev[q*4+3]=v4.w;
    }
  }

  h_a[tid] = 0.0f; h_a[tid + 1024] = 0.0f;
  float h0 = 0.0f, h1 = 0.0f;

  const int la15 = lane & 15;
  const int lg = lane >> 4;

  auto step = [&](int tt, const float* hcur, float* hnxt) {
    float y0 = bf2f(u_lds[(size_t)r0 * UST + tt]);
    float y1 = bf2f(u_lds[(size_t)r1 * UST + tt]);
    #pragma unroll
    for (int k = 0; k < WT; ++k) {
      float hv = *(const float*)((const char*)hcur + ea[k]);
      float va = __builtin_bit_cast(float, ev[k] & 0xffff0000u);
      float vb = __builtin_bit_cast(float, ev[k] << 16);
      y0 = __builtin_fmaf(va, hv, y0);
      y1 = __builtin_fmaf(vb, hv, y1);
    }
    float hn0 = 0.1f * h0 + 0.9f * tanh_fast(y0);
    float hn1 = 0.1f * h1 + 0.9f * tanh_fast(y1);
    hnxt[r0] = hn0; hnxt[r1] = hn1;
    hb[(size_t)tt * HBST + r0] = f2bf(hn0);
    hb[(size_t)tt * HBST + r1] = f2bf(hn1);
    h0 = hn0; h1 = hn1;
    __syncthreads();
  };

  for (int c = 0; c < TT / CH; ++c) {
    const int t0 = c * CH;

    // ---- phase A: u = x_chunk @ Win^T via MFMA; wave wv covers n_store in [wv*128, +128)
    {
      const float* xp = x + ((size_t)b * TT + (t0 + la15)) * NI + (lg << 3);
      float4 x0 = *(const float4*)xp;
      float4 x1 = *(const float4*)(xp + 4);
      union { unsigned short u16[8]; bfvec v; } af;
      af.u16[0]=f2bf(x0.x); af.u16[1]=f2bf(x0.y); af.u16[2]=f2bf(x0.z); af.u16[3]=f2bf(x0.w);
      af.u16[4]=f2bf(x1.x); af.u16[5]=f2bf(x1.y); af.u16[6]=f2bf(x1.z); af.u16[7]=f2bf(x1.w);
      #pragma unroll
      for (int nt = 0; nt < 8; ++nt) {
        int ntg = (wv << 3) + nt;
        union { uint4 q; bfvec v; } bw;
        bw.q = *(const uint4*)(winf + (((size_t)ntg * 64 + lane) << 2));
        f4_t acc = {0.f, 0.f, 0.f, 0.f};
        acc = __builtin_amdgcn_mfma_f32_16x16x32_bf16(af.v, bw.v, acc, 0, 0, 0);
        int n = (ntg << 4) + la15;
        int tl = lg << 2;
        uint32_t lo = (uint32_t)f2bf(acc[0]) | ((uint32_t)f2bf(acc[1]) << 16);
        uint32_t hi = (uint32_t)f2bf(acc[2]) | ((uint32_t)f2bf(acc[3]) << 16);
        uint32_t* up = (uint32_t*)(u_lds + (size_t)n * UST + tl);
        up[0] = lo; up[1] = hi;
      }
    }
    __syncthreads();

    // ---- phase B: 16 recurrence steps (double-buffered h, one barrier per step)
    #pragma unroll 1
    for (int tt = 0; tt < CH; tt += 2) {
      step(tt, h_a, h_b);
      step(tt + 1, h_b, h_a);
    }

    // ---- phase C: out_chunk = hb @ Wout^T via MFMA; wave wv covers K in [wv*128, +128)
    {
      f4_t oa0 = {0.f,0.f,0.f,0.f}, oa1 = {0.f,0.f,0.f,0.f};
      #pragma unroll
      for (int k4 = 0; k4 < 4; ++k4) {
        int kt = (wv << 2) + k4;
        union { uint4 q; bfvec v; } ha, w0, w1;
        ha.q = *(const uint4*)(hb + (size_t)la15 * HBST + (kt << 5) + (lg << 3));
        w0.q = *(const uint4*)(woutf + (((size_t)(kt) * 64 + lane) << 2));
        w1.q = *(const uint4*)(woutf + (((size_t)(64 + kt) * 64 + lane) << 2));
        oa0 = __builtin_amdgcn_mfma_f32_16x16x32_bf16(ha.v, w0.v, oa0, 0, 0, 0);
        oa1 = __builtin_amdgcn_mfma_f32_16x16x32_bf16(ha.v, w1.v, oa1, 0, 0, 0);
      }
      float* os = oscratch + (wv << 9);
      int tb = lg << 2;
      #pragma unroll
      for (int r = 0; r < 4; ++r) os[(tb + r) * 32 + la15] = oa0[r];
      #pragma unroll
      for (int r = 0; r < 4; ++r) os[(tb + r) * 32 + 16 + la15] = oa1[r];
    }
    __syncthreads();
    if (tid < 512) {
      float s = 0.0f;
      #pragma unroll
      for (int w2 = 0; w2 < 16; ++w2) s += oscratch[(w2 << 9) + tid];
      int tg = t0 + (tid >> 5);
      if (tg >= WASH - 1)
        out[((size_t)b * TO + (tg - (WASH - 1))) * NO + (tid & 31)] = s;
    }
    __syncthreads();  // protect u/oscratch before next chunk's phase A
  }
}

extern "C" void kernel_launch(void* const* d_in, const int* in_sizes, int n_in,
                              void* d_out, int out_size, void* d_ws, size_t ws_size,
                              hipStream_t stream) {
  (void)in_sizes; (void)n_in; (void)out_size; (void)ws_size;
  const float* x    = (const float*)d_in[0];
  const float* Win  = (const float*)d_in[1];
  const float* A    = (const float*)d_in[2];
  const float* Wout = (const float*)d_in[3];
  float* out = (float*)d_out;

  char* ws = (char*)d_ws;
  uint32_t* ell   = (uint32_t*)(ws);                 // 196608
  uint32_t* deg   = (uint32_t*)(ws + 196608);        // 8192
  uint32_t* perm  = (uint32_t*)(ws + 204800);        // 8192
  uint32_t* invp  = (uint32_t*)(ws + 212992);        // 8192
  uint32_t* pa    = (uint32_t*)(ws + 221184);        // 1024*24*4 = 98304
  uint32_t* pv    = (uint32_t*)(ws + 319488);        // 98304
  uint32_t* winf  = (uint32_t*)(ws + 417792);        // 131072
  uint32_t* woutf = (uint32_t*)(ws + 548864);        // 131072 (total 679936 B)

  hipFuncSetAttribute((const void*)rec_kernel,
                      hipFuncAttributeMaxDynamicSharedMemorySize, 160 * 1024);

  hipLaunchKernelGGL(build_ell, dim3(512), dim3(256), 0, stream, A, ell, deg);
  hipLaunchKernelGGL(sortperm, dim3(1), dim3(1024), 0, stream, deg, perm, invp);
  hipLaunchKernelGGL(schedule_pairs, dim3(16), dim3(64), 0, stream, ell, deg, perm, invp, pa, pv);
  hipLaunchKernelGGL(build_frags, dim3(256), dim3(256), 0, stream, Win, Wout, perm, winf, woutf);
  hipLaunchKernelGGL(rec_kernel, dim3(16), dim3(1024), 155904, stream,
                     x, pa, pv, winf, woutf, out);
}

// Round 4
// 3569.245 us; speedup vs baseline: 2.1881x; 2.1881x over previous
//
#include <hip/hip_runtime.h>
#include <stdint.h>

// Problem constants (fixed seed, fixed shapes)
#define BB 16
#define TT 2048
#define NI 32
#define NN 2048
#define NO 32
#define WASH 64
#define TO (TT - WASH + 1)   // 1985
#define W 24                 // per-row ELL cap
#define WT 24                // per-thread combined (pair) slot count — COMPILE-TIME trip count
#define CH 16                // time-chunk for fused MFMA GEMMs
#define UST 18               // u_lds row stride (halfwords) -> dword stride 9 (coprime 32)
#define HBST 2056            // hb row stride (halfwords) = 2048 + 8 padding

typedef short bfvec __attribute__((ext_vector_type(8)));   // 8 bf16 in 4 VGPRs
typedef float f4_t  __attribute__((ext_vector_type(4)));

__device__ inline unsigned short f2bf(float f) {
  unsigned int u = __builtin_bit_cast(unsigned int, f);
  unsigned int r = u + 0x7fffu + ((u >> 16) & 1u);   // RNE
  return (unsigned short)(r >> 16);
}
__device__ inline float bf2f(unsigned short s) {
  unsigned int u = ((unsigned int)s) << 16;
  return __builtin_bit_cast(float, u);
}
__device__ inline float tanh_fast(float x) {
  x = fminf(15.f, fmaxf(-15.f, x));
  float e = __expf(x + x);
  float r = __builtin_amdgcn_rcpf(e + 1.0f);
  return (e - 1.0f) * r;
}

// ---------------- K1: dense A -> packed ELL (bf16 val << 16 | byte-offset col, NATURAL cols) ----
__global__ void build_ell(const float* __restrict__ A, uint32_t* __restrict__ ell,
                          uint32_t* __restrict__ deg) {
  int gw = (int)((blockIdx.x * blockDim.x + threadIdx.x) >> 6);  // one wave per row
  int lane = (int)(threadIdx.x & 63);
  if (gw >= NN) return;
  const float* row = A + (size_t)gw * NN;
  int base = 0;
  for (int c = 0; c < NN; c += 64) {
    float v = row[c + lane];
    bool nz = (v != 0.0f);
    unsigned long long mask = __ballot(nz);
    int pre = __popcll(mask & ((1ull << lane) - 1ull));
    if (nz) {
      int idx = base + pre;
      if (idx < W) {
        uint32_t packed = (((uint32_t)f2bf(v)) << 16) | (uint32_t)((c + lane) * 4);
        ell[(size_t)gw * W + idx] = packed;
      }
    }
    base += __popcll(mask);
  }
  int d = base < W ? base : W;
  if (lane == 0) deg[gw] = (uint32_t)d;
  for (int k = d + lane; k < W; k += 64) ell[(size_t)gw * W + k] = 0u;
}

// ---------------- K2: DETERMINISTIC counting (rank) sort by degree -> perm, invp ----------------
__global__ void sortperm(const uint32_t* __restrict__ deg, uint32_t* __restrict__ perm,
                         uint32_t* __restrict__ invp) {
  __shared__ int dg[NN];
  int tid = (int)threadIdx.x;
  dg[tid] = (int)deg[tid];
  dg[tid + 1024] = (int)deg[tid + 1024];
  __syncthreads();
  for (int r = tid; r < NN; r += 1024) {
    int d = dg[r];
    int rank = 0;
    for (int j = 0; j < NN; ++j) {
      int dj = dg[j];
      rank += (dj < d) || (dj == d && j < r);
    }
    perm[rank] = (uint32_t)r;
    invp[r] = (uint32_t)rank;
  }
}

// ---------------- K2b: pair rows (tid, 2047-tid) -> WT fixed slots, PARALLEL (no scheduling) ----
// Per rec-thread tid: concatenate entries of store rows tid (y0 half, val in hi16) and
// 2047-tid (y1 half, val in lo16), cols translated to store order. Pad: val=0, addr spread.
__global__ void build_pairs(const uint32_t* __restrict__ ell, const uint32_t* __restrict__ deg,
                            const uint32_t* __restrict__ perm, const uint32_t* __restrict__ invp,
                            uint32_t* __restrict__ pa, uint32_t* __restrict__ pv) {
  int tid = (int)(blockIdx.x * blockDim.x + threadIdx.x);  // 0..1023
  if (tid >= 1024) return;
  uint32_t a_[WT], v_[WT];
  int n = 0;
  int ro = (int)perm[tid];
  int d = (int)deg[ro]; if (d > W) d = W;
  for (int k = 0; k < d && n < WT; ++k) {
    uint32_t e = ell[(size_t)ro * W + k];
    a_[n] = invp[(e & 0xffffu) >> 2] << 2;
    v_[n] = e & 0xffff0000u;           // y0 half
    ++n;
  }
  ro = (int)perm[2047 - tid];
  d = (int)deg[ro]; if (d > W) d = W;
  for (int k = 0; k < d && n < WT; ++k) {
    uint32_t e = ell[(size_t)ro * W + k];
    a_[n] = invp[(e & 0xffffu) >> 2] << 2;
    v_[n] = e >> 16;                   // y1 half
    ++n;
  }
  for (; n < WT; ++n) { a_[n] = ((uint32_t)((tid + n) & 31)) << 2; v_[n] = 0u; }
  for (int k = 0; k < WT; ++k) {
    pa[(size_t)tid * WT + k] = a_[k];
    pv[(size_t)tid * WT + k] = v_[k];
  }
}

// ---------------- K3: Win/Wout -> MFMA B-fragment order (bf16 pairs), PERMUTED n ----------------
__global__ void build_frags(const float* __restrict__ Win, const float* __restrict__ Wout,
                            const uint32_t* __restrict__ perm,
                            uint32_t* __restrict__ winf, uint32_t* __restrict__ woutf) {
  int f = (int)(blockIdx.x * blockDim.x + threadIdx.x);  // 0..65535
  if (f < 32768) {
    int reg = f & 3, lane = (f >> 2) & 63, ntg = f >> 8;
    int n = (ntg << 4) + (lane & 15);
    int k = ((lane >> 4) << 3) + reg * 2;
    int np = (int)perm[n];
    uint32_t lo = f2bf(Win[(size_t)np * NI + k]);
    uint32_t hi = f2bf(Win[(size_t)np * NI + k + 1]);
    winf[f] = lo | (hi << 16);
  } else {
    int g = f - 32768;
    int reg = g & 3, lane = (g >> 2) & 63, kt = (g >> 8) & 63, ot = g >> 14;
    int o = (ot << 4) + (lane & 15);
    int n = (kt << 5) + ((lane >> 4) << 3) + reg * 2;
    uint32_t lo = f2bf(Wout[(size_t)o * NN + (int)perm[n]]);
    uint32_t hi = f2bf(Wout[(size_t)o * NN + (int)perm[n + 1]]);
    woutf[g] = lo | (hi << 16);
  }
}

// ---------------- K4: fused recurrence (1 workgroup per batch), store-order state ----------------
// LDS: h_a[2048]f32 | h_b[2048]f32 | u[2048][UST]bf16 (overlaid by out-scratch) | hb[CH][HBST]bf16
// STEP is a macro (NOT a lambda): a lambda capture-by-reference of ea/ev takes their address,
// the alloca escapes, SROA fails, and the entry arrays land in scratch (the rounds-1..3 bug).
#define STEP(tt, hcur, hnxt)                                                        \
  {                                                                                 \
    float y0 = bf2f(u_lds[(size_t)r0 * UST + (tt)]);                                \
    float y1 = bf2f(u_lds[(size_t)r1 * UST + (tt)]);                                \
    _Pragma("unroll")                                                               \
    for (int k = 0; k < WT; ++k) {                                                  \
      float hv = *(const float*)((const char*)(hcur) + ea[k]);                      \
      float va = __builtin_bit_cast(float, ev[k] & 0xffff0000u);                    \
      float vb = __builtin_bit_cast(float, ev[k] << 16);                            \
      y0 = __builtin_fmaf(va, hv, y0);                                              \
      y1 = __builtin_fmaf(vb, hv, y1);                                              \
    }                                                                               \
    float hn0 = 0.1f * h0 + 0.9f * tanh_fast(y0);                                   \
    float hn1 = 0.1f * h1 + 0.9f * tanh_fast(y1);                                   \
    (hnxt)[r0] = hn0; (hnxt)[r1] = hn1;                                             \
    hb[(size_t)(tt) * HBST + r0] = f2bf(hn0);                                       \
    hb[(size_t)(tt) * HBST + r1] = f2bf(hn1);                                       \
    h0 = hn0; h1 = hn1;                                                             \
    __syncthreads();                                                                \
  }

__global__ __launch_bounds__(1024, 1) void rec_kernel(
    const float* __restrict__ x,
    const uint32_t* __restrict__ pa, const uint32_t* __restrict__ pv,
    const uint32_t* __restrict__ winf, const uint32_t* __restrict__ woutf,
    float* __restrict__ out) {
  extern __shared__ char smem[];
  float* h_a = (float*)smem;                       //  8192 B
  float* h_b = (float*)(smem + 8192);              //  8192 B
  unsigned short* u_lds = (unsigned short*)(smem + 16384);      // 73728 B
  float* oscratch = (float*)(smem + 16384);                     // overlay (32768 B used)
  unsigned short* hb = (unsigned short*)(smem + 16384 + 73728); // 65792 B (total 155904)

  const int tid = (int)threadIdx.x;
  const int b = (int)blockIdx.x;
  const int lane = tid & 63;
  const int wv = tid >> 6;

  const int r0 = tid;            // store-order rows: all per-step writes conflict-free
  const int r1 = 2047 - tid;

  // Combined pair entry list -> registers (static trip count, no lambda, no escape)
  uint32_t ea[WT], ev[WT];
  {
    const uint4* qa = (const uint4*)(pa + (size_t)tid * WT);
    const uint4* qv = (const uint4*)(pv + (size_t)tid * WT);
    #pragma unroll
    for (int q = 0; q < WT / 4; ++q) {
      uint4 a4 = qa[q]; uint4 v4 = qv[q];
      ea[q*4+0]=a4.x; ea[q*4+1]=a4.y; ea[q*4+2]=a4.z; ea[q*4+3]=a4.w;
      ev[q*4+0]=v4.x; ev[q*4+1]=v4.y; ev[q*4+2]=v4.z; ev[q*4+3]=v4.w;
    }
  }

  h_a[tid] = 0.0f; h_a[tid + 1024] = 0.0f;
  float h0 = 0.0f, h1 = 0.0f;

  const int la15 = lane & 15;
  const int lg = lane >> 4;

  for (int c = 0; c < TT / CH; ++c) {
    const int t0 = c * CH;

    // ---- phase A: u = x_chunk @ Win^T via MFMA; wave wv covers n_store in [wv*128, +128)
    {
      const float* xp = x + ((size_t)b * TT + (t0 + la15)) * NI + (lg << 3);
      float4 x0 = *(const float4*)xp;
      float4 x1 = *(const float4*)(xp + 4);
      union { unsigned short u16[8]; bfvec v; } af;
      af.u16[0]=f2bf(x0.x); af.u16[1]=f2bf(x0.y); af.u16[2]=f2bf(x0.z); af.u16[3]=f2bf(x0.w);
      af.u16[4]=f2bf(x1.x); af.u16[5]=f2bf(x1.y); af.u16[6]=f2bf(x1.z); af.u16[7]=f2bf(x1.w);
      #pragma unroll
      for (int nt = 0; nt < 8; ++nt) {
        int ntg = (wv << 3) + nt;
        union { uint4 q; bfvec v; } bw;
        bw.q = *(const uint4*)(winf + (((size_t)ntg * 64 + lane) << 2));
        f4_t acc = {0.f, 0.f, 0.f, 0.f};
        acc = __builtin_amdgcn_mfma_f32_16x16x32_bf16(af.v, bw.v, acc, 0, 0, 0);
        int n = (ntg << 4) + la15;
        int tl = lg << 2;
        uint32_t lo = (uint32_t)f2bf(acc[0]) | ((uint32_t)f2bf(acc[1]) << 16);
        uint32_t hi = (uint32_t)f2bf(acc[2]) | ((uint32_t)f2bf(acc[3]) << 16);
        uint32_t* up = (uint32_t*)(u_lds + (size_t)n * UST + tl);
        up[0] = lo; up[1] = hi;
      }
    }
    __syncthreads();

    // ---- phase B: 16 recurrence steps (double-buffered h, one barrier per step)
    #pragma unroll 1
    for (int tt = 0; tt < CH; tt += 2) {
      STEP(tt, h_a, h_b);
      STEP(tt + 1, h_b, h_a);
    }

    // ---- phase C: out_chunk = hb @ Wout^T via MFMA; wave wv covers K in [wv*128, +128)
    {
      f4_t oa0 = {0.f,0.f,0.f,0.f}, oa1 = {0.f,0.f,0.f,0.f};
      #pragma unroll
      for (int k4 = 0; k4 < 4; ++k4) {
        int kt = (wv << 2) + k4;
        union { uint4 q; bfvec v; } ha, w0, w1;
        ha.q = *(const uint4*)(hb + (size_t)la15 * HBST + (kt << 5) + (lg << 3));
        w0.q = *(const uint4*)(woutf + (((size_t)(kt) * 64 + lane) << 2));
        w1.q = *(const uint4*)(woutf + (((size_t)(64 + kt) * 64 + lane) << 2));
        oa0 = __builtin_amdgcn_mfma_f32_16x16x32_bf16(ha.v, w0.v, oa0, 0, 0, 0);
        oa1 = __builtin_amdgcn_mfma_f32_16x16x32_bf16(ha.v, w1.v, oa1, 0, 0, 0);
      }
      float* os = oscratch + (wv << 9);
      int tb = lg << 2;
      #pragma unroll
      for (int r = 0; r < 4; ++r) os[(tb + r) * 32 + la15] = oa0[r];
      #pragma unroll
      for (int r = 0; r < 4; ++r) os[(tb + r) * 32 + 16 + la15] = oa1[r];
    }
    __syncthreads();
    if (tid < 512) {
      float s = 0.0f;
      #pragma unroll
      for (int w2 = 0; w2 < 16; ++w2) s += oscratch[(w2 << 9) + tid];
      int tg = t0 + (tid >> 5);
      if (tg >= WASH - 1)
        out[((size_t)b * TO + (tg - (WASH - 1))) * NO + (tid & 31)] = s;
    }
    __syncthreads();  // protect u/oscratch before next chunk's phase A
  }
}

extern "C" void kernel_launch(void* const* d_in, const int* in_sizes, int n_in,
                              void* d_out, int out_size, void* d_ws, size_t ws_size,
                              hipStream_t stream) {
  (void)in_sizes; (void)n_in; (void)out_size; (void)ws_size;
  const float* x    = (const float*)d_in[0];
  const float* Win  = (const float*)d_in[1];
  const float* A    = (const float*)d_in[2];
  const float* Wout = (const float*)d_in[3];
  float* out = (float*)d_out;

  char* ws = (char*)d_ws;
  uint32_t* ell   = (uint32_t*)(ws);                 // 196608
  uint32_t* deg   = (uint32_t*)(ws + 196608);        // 8192
  uint32_t* perm  = (uint32_t*)(ws + 204800);        // 8192
  uint32_t* invp  = (uint32_t*)(ws + 212992);        // 8192
  uint32_t* pa    = (uint32_t*)(ws + 221184);        // 1024*24*4 = 98304
  uint32_t* pv    = (uint32_t*)(ws + 319488);        // 98304
  uint32_t* winf  = (uint32_t*)(ws + 417792);        // 131072
  uint32_t* woutf = (uint32_t*)(ws + 548864);        // 131072 (total 679936 B)

  hipFuncSetAttribute((const void*)rec_kernel,
                      hipFuncAttributeMaxDynamicSharedMemorySize, 160 * 1024);

  hipLaunchKernelGGL(build_ell, dim3(512), dim3(256), 0, stream, A, ell, deg);
  hipLaunchKernelGGL(sortperm, dim3(1), dim3(1024), 0, stream, deg, perm, invp);
  hipLaunchKernelGGL(build_pairs, dim3(4), dim3(256), 0, stream, ell, deg, perm, invp, pa, pv);
  hipLaunchKernelGGL(build_frags, dim3(256), dim3(256), 0, stream, Win, Wout, perm, winf, woutf);
  hipLaunchKernelGGL(rec_kernel, dim3(16), dim3(1024), 155904, stream,
                     x, pa, pv, winf, woutf, out);
}